// Round 1
// baseline (530.176 us; speedup 1.0000x reference)
//
#include <hip/hip_runtime.h>
#include <cstdint>
#include <cstddef>

typedef unsigned short u16;
typedef __attribute__((ext_vector_type(8))) short short8v;   // 8 x bf16 (4 VGPRs)
typedef __attribute__((ext_vector_type(4))) float f32x4;

#define B_   2
#define L_   2048
#define D_   1024
#define NH_  16
#define DH_  64
#define M_   (B_*L_)      /* 4096 */
#define N4_  (4*D_)       /* 4096 */

__device__ __forceinline__ float bf2f(u16 u) {
  union { float f; unsigned int i; } v; v.i = ((unsigned int)u) << 16; return v.f;
}
__device__ __forceinline__ u16 f2bf(float f) {
  union { float f; unsigned int i; } v; v.f = f;
  unsigned int x = v.i;
  return (u16)((x + 0x7fffu + ((x >> 16) & 1u)) >> 16);   // RNE
}
__device__ __forceinline__ float siluf(float x) { return x / (1.0f + __expf(-x)); }

// async global->LDS, 16B per lane. LDS dest = wave-uniform base + lane*16.
__device__ __forceinline__ void gl2lds16(const u16* g, u16* l) {
  __builtin_amdgcn_global_load_lds(
      (const __attribute__((address_space(1))) unsigned int*)(const void*)g,
      (__attribute__((address_space(3))) unsigned int*)(void*)l,
      16, 0, 0);
}

// ---------------------------------------------------------------- convert
__global__ __launch_bounds__(256) void k_convert(const float* __restrict__ x,
                                                 const float* __restrict__ pw,
                                                 const float* __restrict__ ow,
                                                 u16* __restrict__ xb,
                                                 u16* __restrict__ pwb,
                                                 u16* __restrict__ owb) {
  const int NX = M_ * D_ / 4, NP = N4_ * D_ / 4;
  int i = blockIdx.x * 256 + threadIdx.x;   // grid sized exactly
  const float* src; u16* dst; int j;
  if (i < NX)            { src = x;  dst = xb;  j = i; }
  else if (i < NX + NP)  { src = pw; dst = pwb; j = i - NX; }
  else                   { src = ow; dst = owb; j = i - NX - NP; }
  float4 v = ((const float4*)src)[j];
  ushort4 o; o.x = f2bf(v.x); o.y = f2bf(v.y); o.z = f2bf(v.z); o.w = f2bf(v.w);
  ((ushort4*)dst)[j] = o;
}

// ---------------------------------------------------------------- cumsum of rope_lambda
__global__ __launch_bounds__(256) void k_cumsum(const float* __restrict__ lam,
                                                float* __restrict__ pos) {
  int b = blockIdx.x, tid = threadIdx.x;
  const float* in = lam + (size_t)b * L_;
  float* out = pos + (size_t)b * L_;
  float loc[8], s = 0.0f;
#pragma unroll
  for (int i = 0; i < 8; ++i) { loc[i] = in[tid * 8 + i]; s += loc[i]; }
  __shared__ float sb[256];
  sb[tid] = s;
  __syncthreads();
  for (int off = 1; off < 256; off <<= 1) {
    float t = (tid >= off) ? sb[tid - off] : 0.0f;
    __syncthreads();
    sb[tid] += t;
    __syncthreads();
  }
  float run = sb[tid] - s;   // exclusive prefix
#pragma unroll
  for (int i = 0; i < 8; ++i) { run += loc[i]; out[tid * 8 + i] = run; }
}

// ---------------------------------------------------------------- GEMM1: h = silu(x @ pw^T + pb), split u/v/q/k
__global__ __launch_bounds__(256) void k_gemm1(const u16* __restrict__ A,
                                               const u16* __restrict__ Bw,
                                               const float* __restrict__ bias,
                                               u16* __restrict__ hu, u16* __restrict__ hv,
                                               u16* __restrict__ hq, u16* __restrict__ hk) {
  const int K = D_;
  int bn = blockIdx.x, bm = blockIdx.y;
  int tid = threadIdx.x;
  int w = tid >> 6, lane = tid & 63, quad = lane >> 4, r16 = lane & 15;
  __shared__ __align__(16) u16 As[4096], Bs[4096];   // 128x32 each, split across 2 issues
  const u16* gA = A  + (size_t)(bm * 128 + (tid >> 2)) * K + (tid & 3) * 8;
  const u16* gB = Bw + (size_t)(bn * 128 + (tid >> 2)) * K + (tid & 3) * 8;
  f32x4 acc[4][4] = {};
  int wm = w & 1, wn = w >> 1;
  const int rowb = wm * 64, colb = wn * 64;
  for (int kt = 0; kt < K; kt += 32) {
    __syncthreads();
    gl2lds16(gA + kt,                 As + w * 512);
    gl2lds16(gA + kt + (size_t)64 * K, As + 2048 + w * 512);
    gl2lds16(gB + kt,                 Bs + w * 512);
    gl2lds16(gB + kt + (size_t)64 * K, Bs + 2048 + w * 512);
    __syncthreads();
    short8v af[4], bf[4];
#pragma unroll
    for (int mi = 0; mi < 4; ++mi)
      af[mi] = *(const short8v*)(As + (rowb + mi * 16 + r16) * 32 + quad * 8);
#pragma unroll
    for (int ni = 0; ni < 4; ++ni)
      bf[ni] = *(const short8v*)(Bs + (colb + ni * 16 + r16) * 32 + quad * 8);
#pragma unroll
    for (int mi = 0; mi < 4; ++mi)
#pragma unroll
      for (int ni = 0; ni < 4; ++ni)
        acc[mi][ni] = __builtin_amdgcn_mfma_f32_16x16x32_bf16(af[mi], bf[ni], acc[mi][ni], 0, 0, 0);
  }
  // epilogue: +bias, silu, store bf16 into one of 4 split buffers (uniform per block)
  int nb = (bn * 128) >> 10;                 // which of u/v/q/k
  u16* dst = (nb == 0) ? hu : (nb == 1) ? hv : (nb == 2) ? hq : hk;
  int cbase = (bn * 128) & 1023;
  int row0 = bm * 128 + rowb;
#pragma unroll
  for (int ni = 0; ni < 4; ++ni) {
    int gcol = bn * 128 + colb + ni * 16 + r16;
    int lcol = cbase + colb + ni * 16 + r16;
    float bb = bias[gcol];
#pragma unroll
    for (int mi = 0; mi < 4; ++mi)
#pragma unroll
      for (int r = 0; r < 4; ++r) {
        int row = row0 + mi * 16 + quad * 4 + r;
        dst[(size_t)row * D_ + lcol] = f2bf(siluf(acc[mi][ni][r] + bb));
      }
  }
}

// ---------------------------------------------------------------- RoPE + gates -> Q,K in (b,h,l,d)
__global__ __launch_bounds__(256) void k_rope(const u16* __restrict__ hq, const u16* __restrict__ hk,
                                              const float* __restrict__ pos,
                                              const float* __restrict__ qg, const float* __restrict__ kg,
                                              u16* __restrict__ Qb, u16* __restrict__ Kb) {
  int idx = blockIdx.x * 256 + threadIdx.x;   // (bh*2048 + l)*32 + j, exact grid
  int j = idx & 31;
  int l = (idx >> 5) & 2047;
  int bh = idx >> 16;
  int b = bh >> 4, hh = bh & 15;
  int row = b * L_ + l;
  float p = pos[row];
  float inv = __expf(-(float)(2 * j) * (9.210340371976184f / 64.0f));  // 10000^(-2j/64)
  float a = p * inv;
  float c = cosf(a), s = sinf(a);
  const u16* hqr = hq + (size_t)row * D_ + hh * DH_;
  const u16* hkr = hk + (size_t)row * D_ + hh * DH_;
  float qe = bf2f(hqr[2 * j]), qo = bf2f(hqr[2 * j + 1]);
  float ke = bf2f(hkr[2 * j]), ko = bf2f(hkr[2 * j + 1]);
  float qgv = qg[(size_t)row * NH_ + hh];
  float kgv = kg[(size_t)row * NH_ + hh];
  size_t ob = ((size_t)bh * L_ + l) * DH_ + j;
  Qb[ob]      = f2bf((qe * c - qo * s) * qgv);
  Qb[ob + 32] = f2bf((qe * s + qo * c) * qgv);
  Kb[ob]      = f2bf((ke * c - ko * s) * kgv);
  Kb[ob + 32] = f2bf((ke * s + ko * c) * kgv);
}

// ---------------------------------------------------------------- V: gate + transpose to (b,h,d,l)
__global__ __launch_bounds__(256) void k_vtrans(const u16* __restrict__ hv,
                                                const float* __restrict__ vg,
                                                u16* __restrict__ Vtb) {
  int d0 = blockIdx.x * 32, l0 = blockIdx.y * 32, bh = blockIdx.z;
  int b = bh >> 4, hh = bh & 15;
  int tx = threadIdx.x, ty = threadIdx.y;   // block (32,8)
  __shared__ float t[32][33];
#pragma unroll
  for (int p = 0; p < 4; ++p) {
    int lr = p * 8 + ty;
    int row = b * L_ + l0 + lr;
    t[lr][tx] = bf2f(hv[(size_t)row * D_ + hh * DH_ + d0 + tx]) * vg[(size_t)row * NH_ + hh];
  }
  __syncthreads();
#pragma unroll
  for (int p = 0; p < 4; ++p) {
    int dr = p * 8 + ty;
    Vtb[((size_t)bh * DH_ + d0 + dr) * L_ + l0 + tx] = f2bf(t[tx][dr]);
  }
}

// ---------------------------------------------------------------- fused causal gated attention + u-multiply
__global__ __launch_bounds__(256) void k_attn(const u16* __restrict__ Qb, const u16* __restrict__ Kb,
                                              const u16* __restrict__ Vtb, const float* __restrict__ tpb,
                                              const float* __restrict__ hsc, const u16* __restrict__ hu,
                                              u16* __restrict__ A2) {
  int id = blockIdx.x;
  // load-balance swizzle: co-resident pairs (id, id+256) have it-sums = 15
  int halfi = id >> 8, qq = id & 255;
  int it = halfi ? (7 - (qq >> 5)) : (8 + (qq >> 5));
  int bh = qq & 31;
  int b = bh >> 4, hh = bh & 15;
  int tid = threadIdx.x, w = tid >> 6, lane = tid & 63, quad = lane >> 4, r16 = lane & 15;
  __shared__ __align__(16) u16 Qs[8192];    // 128 x 64, split-k (2 x 128x32)
  __shared__ __align__(16) u16 KV[8192];    // K tile then V tile per j-iter
  __shared__ __align__(16) u16 Ps[16384];   // 128 x 128, split-k (4 x 128x32)
  float hs = hsc[hh];
  const size_t qbase = ((size_t)bh * L_ + (size_t)it * 128) * DH_;
#pragma unroll
  for (int s = 0; s < 4; ++s) {
    int e = tid * 8 + s * 2048;
    int sub = e >> 12, rr = (e & 4095) >> 5, kk = e & 31;
    gl2lds16(Qb + qbase + rr * DH_ + sub * 32 + kk, Qs + w * 512 + s * 2048);
  }
  f32x4 accy[2][4] = {};
  int wm = w & 1, wn = w >> 1;
  for (int jt = 0; jt <= it; ++jt) {
    __syncthreads();   // KV free for reuse; (iter 0: also drains Q load)
    const size_t kbase = ((size_t)bh * L_ + (size_t)jt * 128) * DH_;
#pragma unroll
    for (int s = 0; s < 4; ++s) {
      int e = tid * 8 + s * 2048;
      int sub = e >> 12, rr = (e & 4095) >> 5, kk = e & 31;
      gl2lds16(Kb + kbase + rr * DH_ + sub * 32 + kk, KV + w * 512 + s * 2048);
    }
    __syncthreads();   // K (and Q) ready
    f32x4 accs[4][4] = {};
#pragma unroll
    for (int ks = 0; ks < 2; ++ks) {
      short8v af[4], bf[4];
#pragma unroll
      for (int mi = 0; mi < 4; ++mi)
        af[mi] = *(const short8v*)(Qs + ks * 4096 + (wm * 64 + mi * 16 + r16) * 32 + quad * 8);
#pragma unroll
      for (int ni = 0; ni < 4; ++ni)
        bf[ni] = *(const short8v*)(KV + ks * 4096 + (wn * 64 + ni * 16 + r16) * 32 + quad * 8);
#pragma unroll
      for (int mi = 0; mi < 4; ++mi)
#pragma unroll
        for (int ni = 0; ni < 4; ++ni)
          accs[mi][ni] = __builtin_amdgcn_mfma_f32_16x16x32_bf16(af[mi], bf[ni], accs[mi][ni], 0, 0, 0);
    }
    // epilogue: scale, +4*bias, silu, causal mask, pack into Ps (A-operand split-k layout)
#pragma unroll
    for (int ni = 0; ni < 4; ++ni) {
      int lj = wn * 64 + ni * 16 + r16;
      int gj = jt * 128 + lj;
#pragma unroll
      for (int mi = 0; mi < 4; ++mi)
#pragma unroll
        for (int r = 0; r < 4; ++r) {
          int li = wm * 64 + mi * 16 + quad * 4 + r;
          int gi = it * 128 + li;
          float v = accs[mi][ni][r] * hs + 4.0f * tpb[((size_t)b * L_ + gi) * L_ + gj];
          v = siluf(v);
          if (gj > gi) v = 0.0f;
          Ps[(lj >> 5) * 4096 + li * 32 + (lj & 31)] = f2bf(v);
        }
    }
    __syncthreads();   // Ps ready, K reads drained
    // V tile into KV (Vt layout: 64 x 128, split-k -> 4 x 64x32)
#pragma unroll
    for (int s = 0; s < 4; ++s) {
      gl2lds16(Vtb + ((size_t)bh * DH_ + (tid >> 2)) * L_ + (size_t)jt * 128 + s * 32 + (tid & 3) * 8,
               KV + w * 512 + s * 2048);
    }
    __syncthreads();   // V ready
    // y += P @ V : waves split rows (32 each)
#pragma unroll
    for (int ks = 0; ks < 4; ++ks) {
      short8v pa[2], vb[4];
#pragma unroll
      for (int mi = 0; mi < 2; ++mi)
        pa[mi] = *(const short8v*)(Ps + ks * 4096 + (w * 32 + mi * 16 + r16) * 32 + quad * 8);
#pragma unroll
      for (int ni = 0; ni < 4; ++ni)
        vb[ni] = *(const short8v*)(KV + ks * 2048 + (ni * 16 + r16) * 32 + quad * 8);
#pragma unroll
      for (int mi = 0; mi < 2; ++mi)
#pragma unroll
        for (int ni = 0; ni < 4; ++ni)
          accy[mi][ni] = __builtin_amdgcn_mfma_f32_16x16x32_bf16(pa[mi], vb[ni], accy[mi][ni], 0, 0, 0);
    }
  }
  // final epilogue: y * u -> A2 (b, l, h*64+d) bf16
#pragma unroll
  for (int ni = 0; ni < 4; ++ni) {
    int d = ni * 16 + r16;
#pragma unroll
    for (int mi = 0; mi < 2; ++mi)
#pragma unroll
      for (int r = 0; r < 4; ++r) {
        int li = w * 32 + mi * 16 + quad * 4 + r;
        size_t rowg = (size_t)b * L_ + (size_t)it * 128 + li;
        float u = bf2f(hu[rowg * D_ + hh * DH_ + d]);
        A2[rowg * D_ + hh * DH_ + d] = f2bf(accy[mi][ni][r] * u);
      }
  }
}

// ---------------------------------------------------------------- GEMM2: r = (y*u) @ ow^T + ob + x
__global__ __launch_bounds__(256) void k_gemm2(const u16* __restrict__ A,
                                               const u16* __restrict__ Bw,
                                               const float* __restrict__ bias,
                                               const float* __restrict__ xres,
                                               float* __restrict__ out) {
  const int K = D_;
  int bn = blockIdx.x, bm = blockIdx.y;
  int tid = threadIdx.x;
  int w = tid >> 6, lane = tid & 63, quad = lane >> 4, r16 = lane & 15;
  __shared__ __align__(16) u16 As[4096], Bs[4096];
  const u16* gA = A  + (size_t)(bm * 128 + (tid >> 2)) * K + (tid & 3) * 8;
  const u16* gB = Bw + (size_t)(bn * 128 + (tid >> 2)) * K + (tid & 3) * 8;
  f32x4 acc[4][4] = {};
  int wm = w & 1, wn = w >> 1;
  const int rowb = wm * 64, colb = wn * 64;
  for (int kt = 0; kt < K; kt += 32) {
    __syncthreads();
    gl2lds16(gA + kt,                  As + w * 512);
    gl2lds16(gA + kt + (size_t)64 * K, As + 2048 + w * 512);
    gl2lds16(gB + kt,                  Bs + w * 512);
    gl2lds16(gB + kt + (size_t)64 * K, Bs + 2048 + w * 512);
    __syncthreads();
    short8v af[4], bf[4];
#pragma unroll
    for (int mi = 0; mi < 4; ++mi)
      af[mi] = *(const short8v*)(As + (rowb + mi * 16 + r16) * 32 + quad * 8);
#pragma unroll
    for (int ni = 0; ni < 4; ++ni)
      bf[ni] = *(const short8v*)(Bs + (colb + ni * 16 + r16) * 32 + quad * 8);
#pragma unroll
    for (int mi = 0; mi < 4; ++mi)
#pragma unroll
      for (int ni = 0; ni < 4; ++ni)
        acc[mi][ni] = __builtin_amdgcn_mfma_f32_16x16x32_bf16(af[mi], bf[ni], acc[mi][ni], 0, 0, 0);
  }
  int row0 = bm * 128 + rowb, col0 = bn * 128 + colb;
#pragma unroll
  for (int ni = 0; ni < 4; ++ni) {
    int col = col0 + ni * 16 + r16;
    float bb = bias[col];
#pragma unroll
    for (int mi = 0; mi < 4; ++mi)
#pragma unroll
      for (int r = 0; r < 4; ++r) {
        int row = row0 + mi * 16 + quad * 4 + r;
        out[(size_t)row * D_ + col] = acc[mi][ni][r] + bb + xres[(size_t)row * D_ + col];
      }
  }
}

// ---------------------------------------------------------------- LayerNorm (in place on d_out)
__global__ __launch_bounds__(256) void k_ln(float* __restrict__ r,
                                            const float* __restrict__ g,
                                            const float* __restrict__ be) {
  int row = blockIdx.x, tid = threadIdx.x;
  float* pr = r + (size_t)row * D_;
  __shared__ float s1[4], s2[4];
  float v[4];
#pragma unroll
  for (int i = 0; i < 4; ++i) v[i] = pr[i * 256 + tid];
  float s = v[0] + v[1] + v[2] + v[3];
#pragma unroll
  for (int o = 32; o > 0; o >>= 1) s += __shfl_down(s, o, 64);
  if ((tid & 63) == 0) s1[tid >> 6] = s;
  __syncthreads();
  float mu = (s1[0] + s1[1] + s1[2] + s1[3]) * (1.0f / D_);
  float d = 0.0f;
#pragma unroll
  for (int i = 0; i < 4; ++i) { float t = v[i] - mu; d += t * t; }
#pragma unroll
  for (int o = 32; o > 0; o >>= 1) d += __shfl_down(d, o, 64);
  if ((tid & 63) == 0) s2[tid >> 6] = d;
  __syncthreads();
  float var = (s2[0] + s2[1] + s2[2] + s2[3]) * (1.0f / D_);
  float inv = rsqrtf(var + 1e-5f);
#pragma unroll
  for (int i = 0; i < 4; ++i) {
    int c = i * 256 + tid;
    pr[c] = (v[i] - mu) * inv * g[c] + be[c];
  }
}

// ---------------------------------------------------------------- launch
extern "C" void kernel_launch(void* const* d_in, const int* in_sizes, int n_in,
                              void* d_out, int out_size, void* d_ws, size_t ws_size,
                              hipStream_t stream) {
  const float* x   = (const float*)d_in[0];
  // d_in[1] attn_mask: deterministic causal tril -> not read
  // d_in[2] ts: unused by reference
  const float* lam = (const float*)d_in[3];
  const float* qg  = (const float*)d_in[4];
  const float* kg  = (const float*)d_in[5];
  const float* vg  = (const float*)d_in[6];
  const float* tpb = (const float*)d_in[7];
  const float* pw  = (const float*)d_in[8];
  const float* pb  = (const float*)d_in[9];
  const float* ow  = (const float*)d_in[10];
  const float* ob  = (const float*)d_in[11];
  const float* hsc = (const float*)d_in[12];
  const float* lng = (const float*)d_in[13];
  const float* lnb = (const float*)d_in[14];
  float* out = (float*)d_out;

  char* ws = (char*)d_ws;
  // layout (bytes). aliasing: Qb<-xb, Kb<-pwb, Vtb<-hq, A2<-hk (all after last read)
  u16* xb   = (u16*)(ws + 0);          // 8 MB   x bf16
  u16* pwb  = (u16*)(ws + 8388608);    // 8 MB   proj_w bf16
  u16* owb  = (u16*)(ws + 16777216);   // 2 MB   out_w bf16
  u16* hu   = (u16*)(ws + 18874368);   // 8 MB
  u16* hv   = (u16*)(ws + 27262976);   // 8 MB
  u16* hq   = (u16*)(ws + 35651584);   // 8 MB
  u16* hk   = (u16*)(ws + 44040192);   // 8 MB
  float* pos = (float*)(ws + 52428800); // 16 KB
  u16* Qb  = xb;
  u16* Kb  = pwb;
  u16* Vtb = hq;
  u16* A2  = hk;

  k_convert<<<9216, 256, 0, stream>>>(x, pw, ow, xb, pwb, owb);
  k_cumsum<<<2, 256, 0, stream>>>(lam, pos);
  k_gemm1<<<dim3(32, 32), 256, 0, stream>>>(xb, pwb, pb, hu, hv, hq, hk);
  k_rope<<<8192, 256, 0, stream>>>(hq, hk, pos, qg, kg, Qb, Kb);
  k_vtrans<<<dim3(2, 64, 32), dim3(32, 8), 0, stream>>>(hv, vg, Vtb);
  k_attn<<<512, 256, 0, stream>>>(Qb, Kb, Vtb, tpb, hsc, hu, A2);
  k_gemm2<<<dim3(8, 32), 256, 0, stream>>>(A2, owb, ob, x, out);
  k_ln<<<4096, 256, 0, stream>>>(out, lng, lnb);
}

// Round 2
// 379.135 us; speedup vs baseline: 1.3984x; 1.3984x over previous
//
#include <hip/hip_runtime.h>
#include <cstdint>
#include <cstddef>

typedef unsigned short u16;
typedef __attribute__((ext_vector_type(8))) short short8v;   // 8 x bf16 (4 VGPRs)
typedef __attribute__((ext_vector_type(4))) float f32x4;

#define B_   2
#define L_   2048
#define D_   1024
#define NH_  16
#define DH_  64
#define M_   (B_*L_)      /* 4096 */
#define N4_  (4*D_)       /* 4096 */

__device__ __forceinline__ float bf2f(u16 u) {
  union { float f; unsigned int i; } v; v.i = ((unsigned int)u) << 16; return v.f;
}
__device__ __forceinline__ u16 f2bf(float f) {
  union { float f; unsigned int i; } v; v.f = f;
  unsigned int x = v.i;
  return (u16)((x + 0x7fffu + ((x >> 16) & 1u)) >> 16);   // RNE
}
__device__ __forceinline__ float siluf(float x) { return x / (1.0f + __expf(-x)); }

// async global->LDS, 16B per lane. LDS dest = wave-uniform base + lane*16.
__device__ __forceinline__ void gl2lds16(const u16* g, u16* l) {
  __builtin_amdgcn_global_load_lds(
      (const __attribute__((address_space(1))) unsigned int*)(const void*)g,
      (__attribute__((address_space(3))) unsigned int*)(void*)l,
      16, 0, 0);
}

// ---------------------------------------------------------------- convert
__global__ __launch_bounds__(256) void k_convert(const float* __restrict__ x,
                                                 const float* __restrict__ pw,
                                                 const float* __restrict__ ow,
                                                 u16* __restrict__ xb,
                                                 u16* __restrict__ pwb,
                                                 u16* __restrict__ owb) {
  const int NX = M_ * D_ / 4, NP = N4_ * D_ / 4;
  int i = blockIdx.x * 256 + threadIdx.x;   // grid sized exactly
  const float* src; u16* dst; int j;
  if (i < NX)            { src = x;  dst = xb;  j = i; }
  else if (i < NX + NP)  { src = pw; dst = pwb; j = i - NX; }
  else                   { src = ow; dst = owb; j = i - NX - NP; }
  float4 v = ((const float4*)src)[j];
  ushort4 o; o.x = f2bf(v.x); o.y = f2bf(v.y); o.z = f2bf(v.z); o.w = f2bf(v.w);
  ((ushort4*)dst)[j] = o;
}

// ---------------------------------------------------------------- cumsum of rope_lambda
__global__ __launch_bounds__(256) void k_cumsum(const float* __restrict__ lam,
                                                float* __restrict__ pos) {
  int b = blockIdx.x, tid = threadIdx.x;
  const float* in = lam + (size_t)b * L_;
  float* out = pos + (size_t)b * L_;
  float loc[8], s = 0.0f;
#pragma unroll
  for (int i = 0; i < 8; ++i) { loc[i] = in[tid * 8 + i]; s += loc[i]; }
  __shared__ float sb[256];
  sb[tid] = s;
  __syncthreads();
  for (int off = 1; off < 256; off <<= 1) {
    float t = (tid >= off) ? sb[tid - off] : 0.0f;
    __syncthreads();
    sb[tid] += t;
    __syncthreads();
  }
  float run = sb[tid] - s;   // exclusive prefix
#pragma unroll
  for (int i = 0; i < 8; ++i) { run += loc[i]; out[tid * 8 + i] = run; }
}

// ---------------------------------------------------------------- GEMM1: h = silu(x @ pw^T + pb), split u/v/q/k
__global__ __launch_bounds__(256) void k_gemm1(const u16* __restrict__ A,
                                               const u16* __restrict__ Bw,
                                               const float* __restrict__ bias,
                                               u16* __restrict__ hu, u16* __restrict__ hv,
                                               u16* __restrict__ hq, u16* __restrict__ hk) {
  const int K = D_;
  int bn = blockIdx.x, bm = blockIdx.y;
  int tid = threadIdx.x;
  int w = tid >> 6, lane = tid & 63, quad = lane >> 4, r16 = lane & 15;
  __shared__ __align__(16) u16 As[4096], Bs[4096];   // 128x32 each
  const u16* gA = A  + (size_t)(bm * 128 + (tid >> 2)) * K + (tid & 3) * 8;
  const u16* gB = Bw + (size_t)(bn * 128 + (tid >> 2)) * K + (tid & 3) * 8;
  f32x4 acc[4][4] = {};
  int wm = w & 1, wn = w >> 1;
  const int rowb = wm * 64, colb = wn * 64;
  for (int kt = 0; kt < K; kt += 32) {
    __syncthreads();
    gl2lds16(gA + kt,                 As + w * 512);
    gl2lds16(gA + kt + (size_t)64 * K, As + 2048 + w * 512);
    gl2lds16(gB + kt,                 Bs + w * 512);
    gl2lds16(gB + kt + (size_t)64 * K, Bs + 2048 + w * 512);
    __syncthreads();
    short8v af[4], bf[4];
#pragma unroll
    for (int mi = 0; mi < 4; ++mi)
      af[mi] = *(const short8v*)(As + (rowb + mi * 16 + r16) * 32 + quad * 8);
#pragma unroll
    for (int ni = 0; ni < 4; ++ni)
      bf[ni] = *(const short8v*)(Bs + (colb + ni * 16 + r16) * 32 + quad * 8);
#pragma unroll
    for (int mi = 0; mi < 4; ++mi)
#pragma unroll
      for (int ni = 0; ni < 4; ++ni)
        acc[mi][ni] = __builtin_amdgcn_mfma_f32_16x16x32_bf16(af[mi], bf[ni], acc[mi][ni], 0, 0, 0);
  }
  int nb = (bn * 128) >> 10;                 // which of u/v/q/k
  u16* dst = (nb == 0) ? hu : (nb == 1) ? hv : (nb == 2) ? hq : hk;
  int cbase = (bn * 128) & 1023;
  int row0 = bm * 128 + rowb;
#pragma unroll
  for (int ni = 0; ni < 4; ++ni) {
    int gcol = bn * 128 + colb + ni * 16 + r16;
    int lcol = cbase + colb + ni * 16 + r16;
    float bb = bias[gcol];
#pragma unroll
    for (int mi = 0; mi < 4; ++mi)
#pragma unroll
      for (int r = 0; r < 4; ++r) {
        int row = row0 + mi * 16 + quad * 4 + r;
        dst[(size_t)row * D_ + lcol] = f2bf(siluf(acc[mi][ni][r] + bb));
      }
  }
}

// ---------------------------------------------------------------- RoPE + gates (+head_scale into Q) -> Q,K in (b,h,l,d)
__global__ __launch_bounds__(256) void k_rope(const u16* __restrict__ hq, const u16* __restrict__ hk,
                                              const float* __restrict__ pos,
                                              const float* __restrict__ qg, const float* __restrict__ kg,
                                              const float* __restrict__ hsc,
                                              u16* __restrict__ Qb, u16* __restrict__ Kb) {
  int idx = blockIdx.x * 256 + threadIdx.x;   // (bh*2048 + l)*8 + j4, exact grid
  int j4 = idx & 7;
  int l  = (idx >> 3) & 2047;
  int bh = idx >> 14;
  int b = bh >> 4, hh = bh & 15;
  int row = b * L_ + l;
  float p = pos[row];
  float qs = qg[(size_t)row * NH_ + hh] * hsc[hh];
  float kgv = kg[(size_t)row * NH_ + hh];
  const u16* hqr = hq + (size_t)row * D_ + hh * DH_ + j4 * 8;
  const u16* hkr = hk + (size_t)row * D_ + hh * DH_ + j4 * 8;
  short8v qv = *(const short8v*)hqr;
  short8v kv = *(const short8v*)hkr;
  size_t ob = ((size_t)bh * L_ + l) * DH_ + j4 * 4;
  u16 qeo[4], qoo[4], keo[4], koo[4];
#pragma unroll
  for (int t = 0; t < 4; ++t) {
    int j = j4 * 4 + t;
    float inv = __expf(-(float)j * 0.28782313662425574f);  // 10000^(-2j/64)
    float a = p * inv;
    float c, s;
    __sincosf(a, &s, &c);
    float qe = bf2f((u16)qv[2 * t]), qo = bf2f((u16)qv[2 * t + 1]);
    float ke = bf2f((u16)kv[2 * t]), ko = bf2f((u16)kv[2 * t + 1]);
    qeo[t] = f2bf((qe * c - qo * s) * qs);
    qoo[t] = f2bf((qe * s + qo * c) * qs);
    keo[t] = f2bf((ke * c - ko * s) * kgv);
    koo[t] = f2bf((ke * s + ko * c) * kgv);
  }
  *(ushort4*)(Qb + ob)      = make_ushort4(qeo[0], qeo[1], qeo[2], qeo[3]);
  *(ushort4*)(Qb + ob + 32) = make_ushort4(qoo[0], qoo[1], qoo[2], qoo[3]);
  *(ushort4*)(Kb + ob)      = make_ushort4(keo[0], keo[1], keo[2], keo[3]);
  *(ushort4*)(Kb + ob + 32) = make_ushort4(koo[0], koo[1], koo[2], koo[3]);
}

// ---------------------------------------------------------------- V: gate + transpose to (b,h,d,l), 64x64 tiles
__global__ __launch_bounds__(256) void k_vtrans(const u16* __restrict__ hv,
                                                const float* __restrict__ vg,
                                                u16* __restrict__ Vtb) {
  int lt = blockIdx.x;        // 0..31 l-tile
  int bh = blockIdx.y;        // 0..31
  int b = bh >> 4, hh = bh & 15;
  int tid = threadIdx.x;
  __shared__ u16 t[64][68];   // pad to break transpose conflicts
  {
    int r = tid >> 2, cg = tid & 3;
    int row = b * L_ + lt * 64 + r;
    float gv = vg[(size_t)row * NH_ + hh];
    const u16* src = hv + (size_t)row * D_ + hh * DH_ + cg * 16;
    short8v v0 = ((const short8v*)src)[0];
    short8v v1 = ((const short8v*)src)[1];
#pragma unroll
    for (int e = 0; e < 8; ++e) {
      t[r][cg * 16 + e]     = f2bf(bf2f((u16)v0[e]) * gv);
      t[r][cg * 16 + 8 + e] = f2bf(bf2f((u16)v1[e]) * gv);
    }
  }
  __syncthreads();
  {
    int d = tid >> 2, lg = tid & 3;
    short8v o0, o1;
#pragma unroll
    for (int e = 0; e < 8; ++e) o0[e] = (short)t[lg * 16 + e][d];
#pragma unroll
    for (int e = 0; e < 8; ++e) o1[e] = (short)t[lg * 16 + 8 + e][d];
    u16* dst = Vtb + ((size_t)bh * DH_ + d) * L_ + lt * 64 + lg * 16;
    ((short8v*)dst)[0] = o0;
    ((short8v*)dst)[1] = o1;
  }
}

// ---------------------------------------------------------------- fused causal gated attention + u-multiply
// 64-row Q tiles, bias+silu fused into PV A-fragment prep (coalesced float4 bias loads)
__global__ __launch_bounds__(256, 2) void k_attn(const u16* __restrict__ Qb, const u16* __restrict__ Kb,
                                                 const u16* __restrict__ Vtb, const float* __restrict__ tpb,
                                                 const u16* __restrict__ hu, u16* __restrict__ A2) {
  int id = blockIdx.x;
  // heavy/light interleave over dispatch order
  int group = id >> 5, bh = id & 31;
  int i64 = (group & 1) ? (group >> 1) : (31 - (group >> 1));
  int jmax = i64 >> 1;
  int b = bh >> 4, hh = bh & 15;
  int tid = threadIdx.x, w = tid >> 6, lane = tid & 63, quad = lane >> 4, r16 = lane & 15;
  __shared__ __align__(16) u16 Qs[4096];   // 64 x 64  (2 k-slices of 64x32)
  __shared__ __align__(16) u16 Ks[8192];   // 128 x 64 (2 k-slices of 128x32)
  __shared__ __align__(16) u16 Vs[8192];   // 64 x 128 (4 l-slices of 64x32)
  __shared__ __align__(16) u16 Ps[8192];   // 64 x 128 raw S, rotated A-layout
  const size_t qbase = ((size_t)bh * L_ + (size_t)i64 * 64) * DH_;
  // stage Q (2 issues)
#pragma unroll
  for (int s = 0; s < 2; ++s)
    gl2lds16(Qb + qbase + (size_t)(tid >> 2) * DH_ + s * 32 + (tid & 3) * 8,
             Qs + w * 512 + s * 2048);
  f32x4 accy[4] = {};
  int wm = w & 1, wn = w >> 1;
  short8v af[2][2];
  for (int jt = 0; jt <= jmax; ++jt) {
    __syncthreads();   // prior PV done reading Ks/Vs/Ps
    const size_t kbase = ((size_t)bh * L_ + (size_t)jt * 128) * DH_;
#pragma unroll
    for (int s = 0; s < 4; ++s) {
      int e = tid * 8 + s * 2048;
      int sub = e >> 12, rr = (e & 4095) >> 5, kk = e & 31;
      gl2lds16(Kb + kbase + (size_t)rr * DH_ + sub * 32 + kk, Ks + w * 512 + s * 2048);
    }
#pragma unroll
    for (int s = 0; s < 4; ++s)
      gl2lds16(Vtb + ((size_t)bh * DH_ + (tid >> 2)) * L_ + (size_t)jt * 128 + s * 32 + (tid & 3) * 8,
               Vs + w * 512 + s * 2048);
    __syncthreads();   // K,V (and Q on jt=0) ready
    if (jt == 0) {
#pragma unroll
      for (int ks = 0; ks < 2; ++ks)
#pragma unroll
        for (int mi = 0; mi < 2; ++mi)
          af[ks][mi] = *(const short8v*)(Qs + ks * 2048 + (wm * 32 + mi * 16 + r16) * 32 + quad * 8);
    }
    // ---- QK^T -> S (raw, scaled via Q) into Ps
    f32x4 accs[2][4] = {};
    int limN = i64 * 64 + 63 - jt * 128 - wn * 64;   // ni*16 > limN -> slice fully masked
#pragma unroll
    for (int ks = 0; ks < 2; ++ks) {
#pragma unroll
      for (int ni = 0; ni < 4; ++ni) {
        if (ni * 16 > limN) continue;
        short8v bfv = *(const short8v*)(Ks + ks * 4096 + (wn * 64 + ni * 16 + r16) * 32 + quad * 8);
#pragma unroll
        for (int mi = 0; mi < 2; ++mi)
          accs[mi][ni] = __builtin_amdgcn_mfma_f32_16x16x32_bf16(af[ks][mi], bfv, accs[mi][ni], 0, 0, 0);
      }
    }
#pragma unroll
    for (int ni = 0; ni < 4; ++ni) {
      if (ni * 16 > limN) continue;
      int lj = wn * 64 + ni * 16 + r16;
      int ksl = lj >> 5, kk = lj & 31;
      int colp = (kk + quad * 8) & 31;     // rotation: rot(li) = (li>>2 & 3)*8 == quad*8 here
      u16* pp = Ps + ksl * 2048 + colp;
#pragma unroll
      for (int mi = 0; mi < 2; ++mi)
#pragma unroll
        for (int r = 0; r < 4; ++r) {
          int li = wm * 32 + mi * 16 + quad * 4 + r;
          pp[li * 32] = f2bf(accs[mi][ni][r]);
        }
    }
    __syncthreads();   // Ps ready
    // ---- PV with fused bias+silu+mask in A-fragment prep. wave w: rows w*16..w*16+15
    int li = w * 16 + r16;
    int gi = i64 * 64 + li;
    int rotr = ((r16 >> 2) & 3) << 3;
#pragma unroll
    for (int ks = 0; ks < 4; ++ks) {
      if (jt * 128 + ks * 32 > i64 * 64 + w * 16 + 15) continue;  // slice fully masked for this wave
      int colp = (quad * 8 + rotr) & 31;
      short8v sraw = *(const short8v*)(Ps + ks * 2048 + li * 32 + colp);
      const float* bp = tpb + ((size_t)b * L_ + gi) * L_ + jt * 128 + ks * 32 + quad * 8;
      float4 b0 = ((const float4*)bp)[0];
      float4 b1 = ((const float4*)bp)[1];
      float pv[8];
      pv[0] = bf2f((u16)sraw[0]) + 4.0f * b0.x;
      pv[1] = bf2f((u16)sraw[1]) + 4.0f * b0.y;
      pv[2] = bf2f((u16)sraw[2]) + 4.0f * b0.z;
      pv[3] = bf2f((u16)sraw[3]) + 4.0f * b0.w;
      pv[4] = bf2f((u16)sraw[4]) + 4.0f * b1.x;
      pv[5] = bf2f((u16)sraw[5]) + 4.0f * b1.y;
      pv[6] = bf2f((u16)sraw[6]) + 4.0f * b1.z;
      pv[7] = bf2f((u16)sraw[7]) + 4.0f * b1.w;
      int lim = gi - (jt * 128 + ks * 32 + quad * 8);
      short8v pa;
#pragma unroll
      for (int j = 0; j < 8; ++j)
        pa[j] = (short)f2bf((j <= lim) ? siluf(pv[j]) : 0.0f);
      short8v vb[4];
#pragma unroll
      for (int ni = 0; ni < 4; ++ni)
        vb[ni] = *(const short8v*)(Vs + ks * 2048 + (ni * 16 + r16) * 32 + quad * 8);
#pragma unroll
      for (int ni = 0; ni < 4; ++ni)
        accy[ni] = __builtin_amdgcn_mfma_f32_16x16x32_bf16(pa, vb[ni], accy[ni], 0, 0, 0);
    }
  }
  // final epilogue: y * u -> A2 (b, l, h*64+d) bf16
#pragma unroll
  for (int ni = 0; ni < 4; ++ni) {
    int d = ni * 16 + r16;
#pragma unroll
    for (int r = 0; r < 4; ++r) {
      int li = w * 16 + quad * 4 + r;
      size_t rowg = (size_t)b * L_ + (size_t)i64 * 64 + li;
      float u = bf2f(hu[rowg * D_ + hh * DH_ + d]);
      A2[rowg * D_ + hh * DH_ + d] = f2bf(accy[ni][r] * u);
    }
  }
}

// ---------------------------------------------------------------- GEMM2: r = (y*u) @ ow^T + ob + x
__global__ __launch_bounds__(256) void k_gemm2(const u16* __restrict__ A,
                                               const u16* __restrict__ Bw,
                                               const float* __restrict__ bias,
                                               const float* __restrict__ xres,
                                               float* __restrict__ out) {
  const int K = D_;
  int bn = blockIdx.x, bm = blockIdx.y;
  int tid = threadIdx.x;
  int w = tid >> 6, lane = tid & 63, quad = lane >> 4, r16 = lane & 15;
  __shared__ __align__(16) u16 As[4096], Bs[4096];
  const u16* gA = A  + (size_t)(bm * 128 + (tid >> 2)) * K + (tid & 3) * 8;
  const u16* gB = Bw + (size_t)(bn * 128 + (tid >> 2)) * K + (tid & 3) * 8;
  f32x4 acc[4][4] = {};
  int wm = w & 1, wn = w >> 1;
  const int rowb = wm * 64, colb = wn * 64;
  for (int kt = 0; kt < K; kt += 32) {
    __syncthreads();
    gl2lds16(gA + kt,                  As + w * 512);
    gl2lds16(gA + kt + (size_t)64 * K, As + 2048 + w * 512);
    gl2lds16(gB + kt,                  Bs + w * 512);
    gl2lds16(gB + kt + (size_t)64 * K, Bs + 2048 + w * 512);
    __syncthreads();
    short8v af[4], bf[4];
#pragma unroll
    for (int mi = 0; mi < 4; ++mi)
      af[mi] = *(const short8v*)(As + (rowb + mi * 16 + r16) * 32 + quad * 8);
#pragma unroll
    for (int ni = 0; ni < 4; ++ni)
      bf[ni] = *(const short8v*)(Bs + (colb + ni * 16 + r16) * 32 + quad * 8);
#pragma unroll
    for (int mi = 0; mi < 4; ++mi)
#pragma unroll
      for (int ni = 0; ni < 4; ++ni)
        acc[mi][ni] = __builtin_amdgcn_mfma_f32_16x16x32_bf16(af[mi], bf[ni], acc[mi][ni], 0, 0, 0);
  }
  int row0 = bm * 128 + rowb, col0 = bn * 128 + colb;
#pragma unroll
  for (int ni = 0; ni < 4; ++ni) {
    int col = col0 + ni * 16 + r16;
    float bb = bias[col];
#pragma unroll
    for (int mi = 0; mi < 4; ++mi)
#pragma unroll
      for (int r = 0; r < 4; ++r) {
        int row = row0 + mi * 16 + quad * 4 + r;
        out[(size_t)row * D_ + col] = acc[mi][ni][r] + bb + xres[(size_t)row * D_ + col];
      }
  }
}

// ---------------------------------------------------------------- LayerNorm (in place on d_out)
__global__ __launch_bounds__(256) void k_ln(float* __restrict__ r,
                                            const float* __restrict__ g,
                                            const float* __restrict__ be) {
  int row = blockIdx.x, tid = threadIdx.x;
  float* pr = r + (size_t)row * D_;
  __shared__ float s1[4], s2[4];
  float v[4];
#pragma unroll
  for (int i = 0; i < 4; ++i) v[i] = pr[i * 256 + tid];
  float s = v[0] + v[1] + v[2] + v[3];
#pragma unroll
  for (int o = 32; o > 0; o >>= 1) s += __shfl_down(s, o, 64);
  if ((tid & 63) == 0) s1[tid >> 6] = s;
  __syncthreads();
  float mu = (s1[0] + s1[1] + s1[2] + s1[3]) * (1.0f / D_);
  float d = 0.0f;
#pragma unroll
  for (int i = 0; i < 4; ++i) { float t = v[i] - mu; d += t * t; }
#pragma unroll
  for (int o = 32; o > 0; o >>= 1) d += __shfl_down(d, o, 64);
  if ((tid & 63) == 0) s2[tid >> 6] = d;
  __syncthreads();
  float var = (s2[0] + s2[1] + s2[2] + s2[3]) * (1.0f / D_);
  float inv = rsqrtf(var + 1e-5f);
#pragma unroll
  for (int i = 0; i < 4; ++i) {
    int c = i * 256 + tid;
    pr[c] = (v[i] - mu) * inv * g[c] + be[c];
  }
}

// ---------------------------------------------------------------- launch
extern "C" void kernel_launch(void* const* d_in, const int* in_sizes, int n_in,
                              void* d_out, int out_size, void* d_ws, size_t ws_size,
                              hipStream_t stream) {
  const float* x   = (const float*)d_in[0];
  // d_in[1] attn_mask: deterministic causal tril -> not read
  // d_in[2] ts: unused by reference
  const float* lam = (const float*)d_in[3];
  const float* qg  = (const float*)d_in[4];
  const float* kg  = (const float*)d_in[5];
  const float* vg  = (const float*)d_in[6];
  const float* tpb = (const float*)d_in[7];
  const float* pw  = (const float*)d_in[8];
  const float* pb  = (const float*)d_in[9];
  const float* ow  = (const float*)d_in[10];
  const float* ob  = (const float*)d_in[11];
  const float* hsc = (const float*)d_in[12];
  const float* lng = (const float*)d_in[13];
  const float* lnb = (const float*)d_in[14];
  float* out = (float*)d_out;

  char* ws = (char*)d_ws;
  // layout (bytes). aliasing: Qb<-xb, Kb<-pwb, Vtb<-hq, A2<-hk (all after last read)
  u16* xb   = (u16*)(ws + 0);          // 8 MB   x bf16
  u16* pwb  = (u16*)(ws + 8388608);    // 8 MB   proj_w bf16
  u16* owb  = (u16*)(ws + 16777216);   // 2 MB   out_w bf16
  u16* hu   = (u16*)(ws + 18874368);   // 8 MB
  u16* hv   = (u16*)(ws + 27262976);   // 8 MB
  u16* hq   = (u16*)(ws + 35651584);   // 8 MB
  u16* hk   = (u16*)(ws + 44040192);   // 8 MB
  float* pos = (float*)(ws + 52428800); // 16 KB
  u16* Qb  = xb;
  u16* Kb  = pwb;
  u16* Vtb = hq;
  u16* A2  = hk;

  k_convert<<<9216, 256, 0, stream>>>(x, pw, ow, xb, pwb, owb);
  k_cumsum<<<2, 256, 0, stream>>>(lam, pos);
  k_gemm1<<<dim3(32, 32), 256, 0, stream>>>(xb, pwb, pb, hu, hv, hq, hk);
  k_rope<<<2048, 256, 0, stream>>>(hq, hk, pos, qg, kg, hsc, Qb, Kb);
  k_vtrans<<<dim3(32, 32), 256, 0, stream>>>(hv, vg, Vtb);
  k_attn<<<1024, 256, 0, stream>>>(Qb, Kb, Vtb, tpb, hu, A2);
  k_gemm2<<<dim3(8, 32), 256, 0, stream>>>(A2, owb, ob, x, out);
  k_ln<<<4096, 256, 0, stream>>>(out, lng, lnb);
}

// Round 3
// 321.457 us; speedup vs baseline: 1.6493x; 1.1794x over previous
//
#include <hip/hip_runtime.h>
#include <cstdint>
#include <cstddef>

typedef unsigned short u16;
typedef __attribute__((ext_vector_type(8))) short short8v;   // 8 x bf16 (4 VGPRs)
typedef __attribute__((ext_vector_type(4))) float f32x4;

#define B_   2
#define L_   2048
#define D_   1024
#define NH_  16
#define DH_  64
#define M_   (B_*L_)      /* 4096 */
#define N4_  (4*D_)       /* 4096 */

__device__ __forceinline__ float bf2f(u16 u) {
  union { float f; unsigned int i; } v; v.i = ((unsigned int)u) << 16; return v.f;
}
__device__ __forceinline__ u16 f2bf(float f) {
  union { float f; unsigned int i; } v; v.f = f;
  unsigned int x = v.i;
  return (u16)((x + 0x7fffu + ((x >> 16) & 1u)) >> 16);   // RNE
}
__device__ __forceinline__ unsigned int pk_bf16(float a, float b) {
#if __has_builtin(__builtin_amdgcn_cvt_pk_bf16_f32)
  auto r = __builtin_amdgcn_cvt_pk_bf16_f32(a, b);
  union { decltype(r) v; unsigned int u; } c; c.v = r; return c.u;
#else
  return (unsigned int)f2bf(a) | ((unsigned int)f2bf(b) << 16);
#endif
}
__device__ __forceinline__ float siluf(float x) { return x / (1.0f + __expf(-x)); }

// async global->LDS, 16B per lane. LDS dest = wave-uniform base + lane*16.
__device__ __forceinline__ void gl2lds16(const u16* g, u16* l) {
  __builtin_amdgcn_global_load_lds(
      (const __attribute__((address_space(1))) unsigned int*)(const void*)g,
      (__attribute__((address_space(3))) unsigned int*)(void*)l,
      16, 0, 0);
}

// ---------------------------------------------------------------- convert + cumsum (fused)
__global__ __launch_bounds__(256) void k_conv_cum(const float* __restrict__ x,
                                                  const float* __restrict__ pw,
                                                  const float* __restrict__ ow,
                                                  const float* __restrict__ lam,
                                                  u16* __restrict__ xb,
                                                  u16* __restrict__ pwb,
                                                  u16* __restrict__ owb,
                                                  float* __restrict__ pos) {
  const int NX = M_ * D_ / 4, NP = N4_ * D_ / 4;
  int bid = blockIdx.x;
  int tid = threadIdx.x;
  if (bid < 9216) {
    int i = bid * 256 + tid;
    const float* src; u16* dst; int j;
    if (i < NX)            { src = x;  dst = xb;  j = i; }
    else if (i < NX + NP)  { src = pw; dst = pwb; j = i - NX; }
    else                   { src = ow; dst = owb; j = i - NX - NP; }
    float4 v = ((const float4*)src)[j];
    ushort4 o; o.x = f2bf(v.x); o.y = f2bf(v.y); o.z = f2bf(v.z); o.w = f2bf(v.w);
    ((ushort4*)dst)[j] = o;
  } else {
    int b = bid - 9216;
    const float* in = lam + (size_t)b * L_;
    float* out = pos + (size_t)b * L_;
    float loc[8], s = 0.0f;
#pragma unroll
    for (int i = 0; i < 8; ++i) { loc[i] = in[tid * 8 + i]; s += loc[i]; }
    __shared__ float sb[256];
    sb[tid] = s;
    __syncthreads();
    for (int off = 1; off < 256; off <<= 1) {
      float t = (tid >= off) ? sb[tid - off] : 0.0f;
      __syncthreads();
      sb[tid] += t;
      __syncthreads();
    }
    float run = sb[tid] - s;   // exclusive prefix
#pragma unroll
    for (int i = 0; i < 8; ++i) { run += loc[i]; out[tid * 8 + i] = run; }
  }
}

// ---------------------------------------------------------------- GEMM1: h = silu(x @ pw^T + pb), split u/v/q/k
__global__ __launch_bounds__(256) void k_gemm1(const u16* __restrict__ A,
                                               const u16* __restrict__ Bw,
                                               const float* __restrict__ bias,
                                               u16* __restrict__ hu, u16* __restrict__ hv,
                                               u16* __restrict__ hq, u16* __restrict__ hk) {
  const int K = D_;
  int bn = blockIdx.x, bm = blockIdx.y;
  int tid = threadIdx.x;
  int w = tid >> 6, lane = tid & 63, quad = lane >> 4, r16 = lane & 15;
  __shared__ __align__(16) u16 As[4096], Bs[4096];   // 128x32 each
  const u16* gA = A  + (size_t)(bm * 128 + (tid >> 2)) * K + (tid & 3) * 8;
  const u16* gB = Bw + (size_t)(bn * 128 + (tid >> 2)) * K + (tid & 3) * 8;
  f32x4 acc[4][4] = {};
  int wm = w & 1, wn = w >> 1;
  const int rowb = wm * 64, colb = wn * 64;
  for (int kt = 0; kt < K; kt += 32) {
    __syncthreads();
    gl2lds16(gA + kt,                 As + w * 512);
    gl2lds16(gA + kt + (size_t)64 * K, As + 2048 + w * 512);
    gl2lds16(gB + kt,                 Bs + w * 512);
    gl2lds16(gB + kt + (size_t)64 * K, Bs + 2048 + w * 512);
    __syncthreads();
    short8v af[4], bf[4];
#pragma unroll
    for (int mi = 0; mi < 4; ++mi)
      af[mi] = *(const short8v*)(As + (rowb + mi * 16 + r16) * 32 + quad * 8);
#pragma unroll
    for (int ni = 0; ni < 4; ++ni)
      bf[ni] = *(const short8v*)(Bs + (colb + ni * 16 + r16) * 32 + quad * 8);
#pragma unroll
    for (int mi = 0; mi < 4; ++mi)
#pragma unroll
      for (int ni = 0; ni < 4; ++ni)
        acc[mi][ni] = __builtin_amdgcn_mfma_f32_16x16x32_bf16(af[mi], bf[ni], acc[mi][ni], 0, 0, 0);
  }
  int nb = (bn * 128) >> 10;                 // which of u/v/q/k
  u16* dst = (nb == 0) ? hu : (nb == 1) ? hv : (nb == 2) ? hq : hk;
  int cbase = (bn * 128) & 1023;
  int row0 = bm * 128 + rowb;
#pragma unroll
  for (int ni = 0; ni < 4; ++ni) {
    int gcol = bn * 128 + colb + ni * 16 + r16;
    int lcol = cbase + colb + ni * 16 + r16;
    float bb = bias[gcol];
#pragma unroll
    for (int mi = 0; mi < 4; ++mi)
#pragma unroll
      for (int r = 0; r < 4; ++r) {
        int row = row0 + mi * 16 + quad * 4 + r;
        dst[(size_t)row * D_ + lcol] = f2bf(siluf(acc[mi][ni][r] + bb));
      }
  }
}

// ---------------------------------------------------------------- RoPE + gates (+head_scale into Q) and V gate+transpose (fused)
__global__ __launch_bounds__(256) void k_rope_vt(const u16* __restrict__ hq, const u16* __restrict__ hk,
                                                 const u16* __restrict__ hv,
                                                 const float* __restrict__ pos,
                                                 const float* __restrict__ qg, const float* __restrict__ kg,
                                                 const float* __restrict__ vg,
                                                 const float* __restrict__ hsc,
                                                 u16* __restrict__ Qb, u16* __restrict__ Kb,
                                                 u16* __restrict__ Vtb) {
  int bid = blockIdx.x;
  int tid = threadIdx.x;
  if (bid < 2048) {
    int idx = bid * 256 + tid;   // (bh*2048 + l)*8 + j4
    int j4 = idx & 7;
    int l  = (idx >> 3) & 2047;
    int bh = idx >> 14;
    int b = bh >> 4, hh = bh & 15;
    int row = b * L_ + l;
    float p = pos[row];
    float qs = qg[(size_t)row * NH_ + hh] * hsc[hh];
    float kgv = kg[(size_t)row * NH_ + hh];
    const u16* hqr = hq + (size_t)row * D_ + hh * DH_ + j4 * 8;
    const u16* hkr = hk + (size_t)row * D_ + hh * DH_ + j4 * 8;
    short8v qv = *(const short8v*)hqr;
    short8v kv = *(const short8v*)hkr;
    size_t ob = ((size_t)bh * L_ + l) * DH_ + j4 * 4;
    u16 qeo[4], qoo[4], keo[4], koo[4];
#pragma unroll
    for (int t = 0; t < 4; ++t) {
      int j = j4 * 4 + t;
      float inv = __expf(-(float)j * 0.28782313662425574f);  // 10000^(-2j/64)
      float a = p * inv;
      float c, s;
      __sincosf(a, &s, &c);
      float qe = bf2f((u16)qv[2 * t]), qo = bf2f((u16)qv[2 * t + 1]);
      float ke = bf2f((u16)kv[2 * t]), ko = bf2f((u16)kv[2 * t + 1]);
      qeo[t] = f2bf((qe * c - qo * s) * qs);
      qoo[t] = f2bf((qe * s + qo * c) * qs);
      keo[t] = f2bf((ke * c - ko * s) * kgv);
      koo[t] = f2bf((ke * s + ko * c) * kgv);
    }
    *(ushort4*)(Qb + ob)      = make_ushort4(qeo[0], qeo[1], qeo[2], qeo[3]);
    *(ushort4*)(Qb + ob + 32) = make_ushort4(qoo[0], qoo[1], qoo[2], qoo[3]);
    *(ushort4*)(Kb + ob)      = make_ushort4(keo[0], keo[1], keo[2], keo[3]);
    *(ushort4*)(Kb + ob + 32) = make_ushort4(koo[0], koo[1], koo[2], koo[3]);
  } else {
    int b2 = bid - 2048;
    int lt = b2 & 31;           // l-tile
    int bh = b2 >> 5;
    int b = bh >> 4, hh = bh & 15;
    __shared__ u16 t[64][68];   // pad to break transpose conflicts
    {
      int r = tid >> 2, cg = tid & 3;
      int row = b * L_ + lt * 64 + r;
      float gv = vg[(size_t)row * NH_ + hh];
      const u16* src = hv + (size_t)row * D_ + hh * DH_ + cg * 16;
      short8v v0 = ((const short8v*)src)[0];
      short8v v1 = ((const short8v*)src)[1];
#pragma unroll
      for (int e = 0; e < 8; ++e) {
        t[r][cg * 16 + e]     = f2bf(bf2f((u16)v0[e]) * gv);
        t[r][cg * 16 + 8 + e] = f2bf(bf2f((u16)v1[e]) * gv);
      }
    }
    __syncthreads();
    {
      int d = tid >> 2, lg = tid & 3;
      short8v o0, o1;
#pragma unroll
      for (int e = 0; e < 8; ++e) o0[e] = (short)t[lg * 16 + e][d];
#pragma unroll
      for (int e = 0; e < 8; ++e) o1[e] = (short)t[lg * 16 + 8 + e][d];
      u16* dst = Vtb + ((size_t)bh * DH_ + d) * L_ + lt * 64 + lg * 16;
      ((short8v*)dst)[0] = o0;
      ((short8v*)dst)[1] = o1;
    }
  }
}

// ---------------------------------------------------------------- fused causal gated attention + u-multiply
// v3: Q in regs, 48 KB LDS -> 3 blocks/CU, 2 barriers/iter, loads issued under compute
__global__ __launch_bounds__(256, 3) void k_attn(const u16* __restrict__ Qb, const u16* __restrict__ Kb,
                                                 const u16* __restrict__ Vtb, const float* __restrict__ tpb,
                                                 const u16* __restrict__ hu, u16* __restrict__ A2) {
  int id = blockIdx.x;
  int group = id >> 5, bh = id & 31;
  int i64 = (group & 1) ? (group >> 1) : (31 - (group >> 1));
  int jmax = i64 >> 1;
  int b = bh >> 4, hh = bh & 15;
  int tid = threadIdx.x, w = tid >> 6, lane = tid & 63, quad = lane >> 4, r16 = lane & 15;
  __shared__ __align__(16) u16 Ks[8192];   // 128 x 64 (2 k-slices of 128x32)
  __shared__ __align__(16) u16 Vs[8192];   // 64 x 128 (4 l-slices of 64x32)
  __shared__ __align__(16) u16 Ps[8192];   // 64 x 128 bf16 S, rotated A-layout
  int wm = w & 1, wn = w >> 1;
  // Q fragments direct from global (once per block)
  const u16* qtile = Qb + ((size_t)bh * L_ + (size_t)i64 * 64) * DH_;
  short8v af[2][2];
#pragma unroll
  for (int ks = 0; ks < 2; ++ks)
#pragma unroll
    for (int mi = 0; mi < 2; ++mi)
      af[ks][mi] = *(const short8v*)(qtile + (size_t)(wm * 32 + mi * 16 + r16) * DH_ + ks * 32 + quad * 8);
  f32x4 accy[4] = {};
  int li = w * 16 + r16;                 // PV row (A-operand m)
  int gi = i64 * 64 + li;
  int gimax = i64 * 64 + w * 16 + 15;    // wave's max global row
  int rotr = ((r16 >> 2) & 3) << 3;
  const float* bprow = tpb + ((size_t)b * L_ + gi) * L_;
  const size_t bhbase = (size_t)bh * L_ * DH_;
  // prologue: stage K(0)
#pragma unroll
  for (int s = 0; s < 4; ++s) {
    int e = tid * 8 + s * 2048;
    int sub = e >> 12, rr = (e & 4095) >> 5, kk = e & 31;
    gl2lds16(Kb + bhbase + (size_t)rr * DH_ + sub * 32 + kk, Ks + w * 512 + s * 2048);
  }
  for (int jt = 0; jt <= jmax; ++jt) {
    __syncthreads();   // b1: prior PV done (Vs,Ps free); K(jt) drained (hidden under prior PV)
    // stage V(jt)
#pragma unroll
    for (int s = 0; s < 4; ++s)
      gl2lds16(Vtb + bhbase + (size_t)(tid >> 2) * L_ + (size_t)jt * 128 + s * 32 + (tid & 3) * 8,
               Vs + w * 512 + s * 2048);
    // bias prefetch into regs (drains free at b2)
    float4 bb[4][2];
#pragma unroll
    for (int ks = 0; ks < 4; ++ks) {
      if (jt * 128 + ks * 32 > gimax) continue;
      const float* bp = bprow + jt * 128 + ks * 32 + quad * 8;
      bb[ks][0] = ((const float4*)bp)[0];
      bb[ks][1] = ((const float4*)bp)[1];
    }
    // ---- QK^T -> S (raw, scaled via Q) into Ps (K(jt) already resident)
    f32x4 accs[2][4] = {};
    int limN = i64 * 64 + 63 - jt * 128 - wn * 64;   // ni*16 > limN -> slice fully masked
#pragma unroll
    for (int ks = 0; ks < 2; ++ks) {
#pragma unroll
      for (int ni = 0; ni < 4; ++ni) {
        if (ni * 16 > limN) continue;
        short8v bfv = *(const short8v*)(Ks + ks * 4096 + (wn * 64 + ni * 16 + r16) * 32 + quad * 8);
#pragma unroll
        for (int mi = 0; mi < 2; ++mi)
          accs[mi][ni] = __builtin_amdgcn_mfma_f32_16x16x32_bf16(af[ks][mi], bfv, accs[mi][ni], 0, 0, 0);
      }
    }
#pragma unroll
    for (int ni = 0; ni < 4; ++ni) {
      if (ni * 16 > limN) continue;
      int lj = wn * 64 + ni * 16 + r16;
      u16* pp = Ps + (lj >> 5) * 2048 + (((lj & 31) + quad * 8) & 31);
#pragma unroll
      for (int mi = 0; mi < 2; ++mi) {
        unsigned int p01 = pk_bf16(accs[mi][ni][0], accs[mi][ni][1]);
        unsigned int p23 = pk_bf16(accs[mi][ni][2], accs[mi][ni][3]);
        int li0 = (wm * 32 + mi * 16 + quad * 4) * 32;
        pp[li0]      = (u16)p01;
        pp[li0 + 32] = (u16)(p01 >> 16);
        pp[li0 + 64] = (u16)p23;
        pp[li0 + 96] = (u16)(p23 >> 16);
      }
    }
    __syncthreads();   // b2: Ps ready + V(jt) drained (hidden under QK) + bias in regs
    // stage K(jt+1) now (Ks free after b2); drains at next b1, hidden under PV
    if (jt < jmax) {
      size_t kb2 = bhbase + (size_t)(jt + 1) * 128 * DH_;
#pragma unroll
      for (int s = 0; s < 4; ++s) {
        int e = tid * 8 + s * 2048;
        int sub = e >> 12, rr = (e & 4095) >> 5, kk = e & 31;
        gl2lds16(Kb + kb2 + (size_t)rr * DH_ + sub * 32 + kk, Ks + w * 512 + s * 2048);
      }
    }
    // ---- PV with fused bias+silu+mask in A-fragment prep
#pragma unroll
    for (int ks = 0; ks < 4; ++ks) {
      if (jt * 128 + ks * 32 > gimax) continue;
      int colp = (quad * 8 + rotr) & 31;
      short8v sraw = *(const short8v*)(Ps + ks * 2048 + li * 32 + colp);
      int lim = gi - (jt * 128 + ks * 32 + quad * 8);
      float sv[8];
      sv[0] = siluf(fmaf(4.0f, bb[ks][0].x, bf2f((u16)sraw[0])));
      sv[1] = siluf(fmaf(4.0f, bb[ks][0].y, bf2f((u16)sraw[1])));
      sv[2] = siluf(fmaf(4.0f, bb[ks][0].z, bf2f((u16)sraw[2])));
      sv[3] = siluf(fmaf(4.0f, bb[ks][0].w, bf2f((u16)sraw[3])));
      sv[4] = siluf(fmaf(4.0f, bb[ks][1].x, bf2f((u16)sraw[4])));
      sv[5] = siluf(fmaf(4.0f, bb[ks][1].y, bf2f((u16)sraw[5])));
      sv[6] = siluf(fmaf(4.0f, bb[ks][1].z, bf2f((u16)sraw[6])));
      sv[7] = siluf(fmaf(4.0f, bb[ks][1].w, bf2f((u16)sraw[7])));
#pragma unroll
      for (int j = 0; j < 8; ++j) if (j > lim) sv[j] = 0.0f;
      union { short8v v; unsigned int u[4]; } pa;
      pa.u[0] = pk_bf16(sv[0], sv[1]);
      pa.u[1] = pk_bf16(sv[2], sv[3]);
      pa.u[2] = pk_bf16(sv[4], sv[5]);
      pa.u[3] = pk_bf16(sv[6], sv[7]);
      short8v vb[4];
#pragma unroll
      for (int ni = 0; ni < 4; ++ni)
        vb[ni] = *(const short8v*)(Vs + ks * 2048 + (ni * 16 + r16) * 32 + quad * 8);
#pragma unroll
      for (int ni = 0; ni < 4; ++ni)
        accy[ni] = __builtin_amdgcn_mfma_f32_16x16x32_bf16(pa.v, vb[ni], accy[ni], 0, 0, 0);
    }
  }
  // final epilogue: y * u -> A2 (b, l, h*64+d) bf16
#pragma unroll
  for (int ni = 0; ni < 4; ++ni) {
    int d = ni * 16 + r16;
#pragma unroll
    for (int r = 0; r < 4; ++r) {
      int lr = w * 16 + quad * 4 + r;
      size_t rowg = (size_t)b * L_ + (size_t)i64 * 64 + lr;
      float u = bf2f(hu[rowg * D_ + hh * DH_ + d]);
      A2[rowg * D_ + hh * DH_ + d] = f2bf(accy[ni][r] * u);
    }
  }
}

// ---------------------------------------------------------------- GEMM2: r = (y*u) @ ow^T + ob + x
__global__ __launch_bounds__(256) void k_gemm2(const u16* __restrict__ A,
                                               const u16* __restrict__ Bw,
                                               const float* __restrict__ bias,
                                               const float* __restrict__ xres,
                                               float* __restrict__ out) {
  const int K = D_;
  int bn = blockIdx.x, bm = blockIdx.y;
  int tid = threadIdx.x;
  int w = tid >> 6, lane = tid & 63, quad = lane >> 4, r16 = lane & 15;
  __shared__ __align__(16) u16 As[4096], Bs[4096];
  const u16* gA = A  + (size_t)(bm * 128 + (tid >> 2)) * K + (tid & 3) * 8;
  const u16* gB = Bw + (size_t)(bn * 128 + (tid >> 2)) * K + (tid & 3) * 8;
  f32x4 acc[4][4] = {};
  int wm = w & 1, wn = w >> 1;
  const int rowb = wm * 64, colb = wn * 64;
  for (int kt = 0; kt < K; kt += 32) {
    __syncthreads();
    gl2lds16(gA + kt,                  As + w * 512);
    gl2lds16(gA + kt + (size_t)64 * K, As + 2048 + w * 512);
    gl2lds16(gB + kt,                  Bs + w * 512);
    gl2lds16(gB + kt + (size_t)64 * K, Bs + 2048 + w * 512);
    __syncthreads();
    short8v af[4], bf[4];
#pragma unroll
    for (int mi = 0; mi < 4; ++mi)
      af[mi] = *(const short8v*)(As + (rowb + mi * 16 + r16) * 32 + quad * 8);
#pragma unroll
    for (int ni = 0; ni < 4; ++ni)
      bf[ni] = *(const short8v*)(Bs + (colb + ni * 16 + r16) * 32 + quad * 8);
#pragma unroll
    for (int mi = 0; mi < 4; ++mi)
#pragma unroll
      for (int ni = 0; ni < 4; ++ni)
        acc[mi][ni] = __builtin_amdgcn_mfma_f32_16x16x32_bf16(af[mi], bf[ni], acc[mi][ni], 0, 0, 0);
  }
  int row0 = bm * 128 + rowb, col0 = bn * 128 + colb;
#pragma unroll
  for (int ni = 0; ni < 4; ++ni) {
    int col = col0 + ni * 16 + r16;
    float bb = bias[col];
#pragma unroll
    for (int mi = 0; mi < 4; ++mi)
#pragma unroll
      for (int r = 0; r < 4; ++r) {
        int row = row0 + mi * 16 + quad * 4 + r;
        out[(size_t)row * D_ + col] = acc[mi][ni][r] + bb + xres[(size_t)row * D_ + col];
      }
  }
}

// ---------------------------------------------------------------- LayerNorm (in place on d_out)
__global__ __launch_bounds__(256) void k_ln(float* __restrict__ r,
                                            const float* __restrict__ g,
                                            const float* __restrict__ be) {
  int row = blockIdx.x, tid = threadIdx.x;
  float* pr = r + (size_t)row * D_;
  __shared__ float s1[4], s2[4];
  float v[4];
#pragma unroll
  for (int i = 0; i < 4; ++i) v[i] = pr[i * 256 + tid];
  float s = v[0] + v[1] + v[2] + v[3];
#pragma unroll
  for (int o = 32; o > 0; o >>= 1) s += __shfl_down(s, o, 64);
  if ((tid & 63) == 0) s1[tid >> 6] = s;
  __syncthreads();
  float mu = (s1[0] + s1[1] + s1[2] + s1[3]) * (1.0f / D_);
  float d = 0.0f;
#pragma unroll
  for (int i = 0; i < 4; ++i) { float t = v[i] - mu; d += t * t; }
#pragma unroll
  for (int o = 32; o > 0; o >>= 1) d += __shfl_down(d, o, 64);
  if ((tid & 63) == 0) s2[tid >> 6] = d;
  __syncthreads();
  float var = (s2[0] + s2[1] + s2[2] + s2[3]) * (1.0f / D_);
  float inv = rsqrtf(var + 1e-5f);
#pragma unroll
  for (int i = 0; i < 4; ++i) {
    int c = i * 256 + tid;
    pr[c] = (v[i] - mu) * inv * g[c] + be[c];
  }
}

// ---------------------------------------------------------------- launch
extern "C" void kernel_launch(void* const* d_in, const int* in_sizes, int n_in,
                              void* d_out, int out_size, void* d_ws, size_t ws_size,
                              hipStream_t stream) {
  const float* x   = (const float*)d_in[0];
  // d_in[1] attn_mask: deterministic causal tril -> not read
  // d_in[2] ts: unused by reference
  const float* lam = (const float*)d_in[3];
  const float* qg  = (const float*)d_in[4];
  const float* kg  = (const float*)d_in[5];
  const float* vg  = (const float*)d_in[6];
  const float* tpb = (const float*)d_in[7];
  const float* pw  = (const float*)d_in[8];
  const float* pb  = (const float*)d_in[9];
  const float* ow  = (const float*)d_in[10];
  const float* ob  = (const float*)d_in[11];
  const float* hsc = (const float*)d_in[12];
  const float* lng = (const float*)d_in[13];
  const float* lnb = (const float*)d_in[14];
  float* out = (float*)d_out;

  char* ws = (char*)d_ws;
  // layout (bytes). aliasing: Qb<-xb, Kb<-pwb, Vtb<-hq, A2<-hk (all after last read)
  u16* xb   = (u16*)(ws + 0);          // 8 MB   x bf16
  u16* pwb  = (u16*)(ws + 8388608);    // 8 MB   proj_w bf16
  u16* owb  = (u16*)(ws + 16777216);   // 2 MB   out_w bf16
  u16* hu   = (u16*)(ws + 18874368);   // 8 MB
  u16* hv   = (u16*)(ws + 27262976);   // 8 MB
  u16* hq   = (u16*)(ws + 35651584);   // 8 MB
  u16* hk   = (u16*)(ws + 44040192);   // 8 MB
  float* pos = (float*)(ws + 52428800); // 16 KB
  u16* Qb  = xb;
  u16* Kb  = pwb;
  u16* Vtb = hq;
  u16* A2  = hk;

  k_conv_cum<<<9218, 256, 0, stream>>>(x, pw, ow, lam, xb, pwb, owb, pos);
  k_gemm1<<<dim3(32, 32), 256, 0, stream>>>(xb, pwb, pb, hu, hv, hq, hk);
  k_rope_vt<<<3072, 256, 0, stream>>>(hq, hk, hv, pos, qg, kg, vg, hsc, Qb, Kb, Vtb);
  k_attn<<<1024, 256, 0, stream>>>(Qb, Kb, Vtb, tpb, hu, A2);
  k_gemm2<<<dim3(8, 32), 256, 0, stream>>>(A2, owb, ob, x, out);
  k_ln<<<4096, 256, 0, stream>>>(out, lng, lnb);
}